// Round 1
// baseline (248.253 us; speedup 1.0000x reference)
//
#include <hip/hip_runtime.h>
#include <hip/hip_bf16.h>
#include <stdint.h>

typedef __bf16 bf16;
typedef __bf16 bf16x8 __attribute__((ext_vector_type(8)));
typedef __bf16 bf16x4 __attribute__((ext_vector_type(4)));
typedef float f32x4 __attribute__((ext_vector_type(4)));

#define MFMA16(a, b, c) __builtin_amdgcn_mfma_f32_16x16x32_bf16(a, b, c, 0, 0, 0)

__device__ __forceinline__ void gload_lds16(const void* g, void* l) {
  __builtin_amdgcn_global_load_lds(
      (const __attribute__((address_space(1))) void*)g,
      (__attribute__((address_space(3))) void*)l, 16, 0, 0);
}

// ---------------- prep kernels ----------------

__global__ void f32_to_bf16_kernel(const float* __restrict__ in,
                                   bf16* __restrict__ out, int n) {
  int i = (blockIdx.x * blockDim.x + threadIdx.x) * 4;
  if (i >= n) return;
  const float4 v = *(const float4*)(in + i);
  bf16x4 o = {(bf16)v.x, (bf16)v.y, (bf16)v.z, (bf16)v.w};
  *(bf16x4*)(out + i) = o;
}

// in: fp32 [R][C]  ->  out: bf16 [C][R]
__global__ void transpose_to_bf16(const float* __restrict__ in,
                                  bf16* __restrict__ out, int R, int C) {
  __shared__ float t[32][33];
  const int tx = threadIdx.x, ty = threadIdx.y;
  const int c0 = blockIdx.x * 32, r0 = blockIdx.y * 32;
  for (int i = 0; i < 32; i += 8)
    t[ty + i][tx] = in[(size_t)(r0 + ty + i) * C + c0 + tx];
  __syncthreads();
  for (int i = 0; i < 32; i += 8)
    out[(size_t)(c0 + ty + i) * R + r0 + tx] = (bf16)t[tx][ty + i];
}

// ---------------- GEMM: C[M,N] = A[M,K] * Bt[N,K]^T + bias ----------------
// EPI=0: bf16 out (qkv) + scatter V^T ;  EPI=1: fp32 out (proj)

template <int EPI>
__global__ __launch_bounds__(256, 2) void gemm_bt(
    const bf16* __restrict__ A, const bf16* __restrict__ Bt,
    const float* __restrict__ bias, void* __restrict__ Cout,
    bf16* __restrict__ vT, int M, int N, int K) {
  __shared__ bf16 lA[128 * 64];
  __shared__ bf16 lB[128 * 64];
  const int tid = threadIdx.x;
  const int wid = tid >> 6, lane = tid & 63;
  const int l15 = lane & 15, g = lane >> 4;
  const int m0 = blockIdx.y * 128, n0 = blockIdx.x * 128;
  const int wr = wid >> 1, wc = wid & 1;

  f32x4 acc[4][4] = {};

  const int soff = wid * 4096 + lane * 16;  // byte offset in tile per lane
  for (int kt = 0; kt < K; kt += 64) {
    for (int c = 0; c < 4; ++c) {
      const int off = soff + c * 1024;
      const int e = off >> 1;
      const int r = e >> 6, col = e & 63;
      gload_lds16(A + (size_t)(m0 + r) * K + kt + col, (char*)lA + off);
      gload_lds16(Bt + (size_t)(n0 + r) * K + kt + col, (char*)lB + off);
    }
    asm volatile("s_waitcnt vmcnt(0)" ::: "memory");
    __syncthreads();
    for (int kk = 0; kk < 2; ++kk) {
      const int ko = kk * 32 + g * 8;
      bf16x8 af[4], bfr[4];
      for (int mi = 0; mi < 4; ++mi)
        af[mi] = *(const bf16x8*)(lA + (wr * 64 + mi * 16 + l15) * 64 + ko);
      for (int ni = 0; ni < 4; ++ni)
        bfr[ni] = *(const bf16x8*)(lB + (wc * 64 + ni * 16 + l15) * 64 + ko);
      for (int mi = 0; mi < 4; ++mi)
        for (int ni = 0; ni < 4; ++ni)
          acc[mi][ni] = MFMA16(af[mi], bfr[ni], acc[mi][ni]);
    }
    __syncthreads();
  }

  for (int mi = 0; mi < 4; ++mi) {
    const int rbase = m0 + wr * 64 + mi * 16 + g * 4;
    for (int ni = 0; ni < 4; ++ni) {
      const int cc = n0 + wc * 64 + ni * 16 + l15;
      const float bv = bias[cc];
      for (int rg = 0; rg < 4; ++rg) {
        const int r = rbase + rg;
        const float v = acc[mi][ni][rg] + bv;
        if (EPI == 0) {
          const bf16 bb = (bf16)v;
          ((bf16*)Cout)[(size_t)r * N + cc] = bb;
          if (cc >= 2048) {  // V section -> also write V^T [b,h,d,s]
            const int hd_ = cc - 2048;
            const int b = r >> 11, s = r & 2047;
            vT[((size_t)(b * 16 + (hd_ >> 6)) * 64 + (hd_ & 63)) * 2048 + s] = bb;
          }
        } else {
          ((float*)Cout)[(size_t)r * N + cc] = v;
        }
      }
    }
  }
}

// ---------------- attention ----------------
// grid: (S/32=64, NH=16, B=2), block 256 (4 waves).
// Each block: 32 q-rows of one (b,h). Each wave owns a 128-key slice of every
// 512-key chunk. Per chunk: S=QK^T in regs -> exact per-chunk softmax
// (in-reg + shfl + cross-wave LDS stats) -> P to LDS (layout transpose) ->
// O_w += P @ V (V^T from global). Final: cross-wave reduce, *0.25, ctx bf16.

__global__ __launch_bounds__(256, 2) void attn_kernel(
    const bf16* __restrict__ qkv, const bf16* __restrict__ vT,
    bf16* __restrict__ ctx) {
  __shared__ __align__(16) bf16 P[32][520];
  __shared__ float smax[4][32];
  __shared__ float ssum[4][32];

  const int tid = threadIdx.x;
  const int wid = tid >> 6, lane = tid & 63;
  const int l15 = lane & 15, g = lane >> 4;
  const int qt = blockIdx.x, h = blockIdx.y, b = blockIdx.z;
  const int rowbase = b * 2048 + qt * 32;

  const bf16* qptr = qkv + (size_t)rowbase * 3072 + h * 64;
  bf16x8 Qf[2][2];
  for (int m = 0; m < 2; ++m)
    for (int kk = 0; kk < 2; ++kk)
      Qf[m][kk] =
          *(const bf16x8*)(qptr + (size_t)(m * 16 + l15) * 3072 + kk * 32 + g * 8);

  f32x4 Oacc[2][4] = {};

  for (int j = 0; j < 4; ++j) {
    const bf16* kptr = qkv + (size_t)(b * 2048 + j * 512) * 3072 + 1024 + h * 64;
    f32x4 sacc[8][2] = {};
    for (int t = 0; t < 8; ++t) {
      const int key0 = wid * 128 + t * 16;
      for (int kk = 0; kk < 2; ++kk) {
        const bf16x8 Kf = *(const bf16x8*)(kptr + (size_t)(key0 + l15) * 3072 +
                                           kk * 32 + g * 8);
        for (int m = 0; m < 2; ++m)
          sacc[t][m] = MFMA16(Qf[m][kk], Kf, sacc[t][m]);
      }
    }
    float rmax[2][4], rsum[2][4];
    for (int m = 0; m < 2; ++m)
      for (int rg = 0; rg < 4; ++rg) {
        float v = sacc[0][m][rg];
        for (int t = 1; t < 8; ++t) v = fmaxf(v, sacc[t][m][rg]);
        v = fmaxf(v, __shfl_xor(v, 1));
        v = fmaxf(v, __shfl_xor(v, 2));
        v = fmaxf(v, __shfl_xor(v, 4));
        v = fmaxf(v, __shfl_xor(v, 8));
        rmax[m][rg] = v;
      }
    if (l15 == 0)
      for (int m = 0; m < 2; ++m)
        for (int rg = 0; rg < 4; ++rg)
          smax[wid][m * 16 + g * 4 + rg] = rmax[m][rg];
    __syncthreads();
    for (int m = 0; m < 2; ++m)
      for (int rg = 0; rg < 4; ++rg) {
        const int row = m * 16 + g * 4 + rg;
        rmax[m][rg] = fmaxf(fmaxf(smax[0][row], smax[1][row]),
                            fmaxf(smax[2][row], smax[3][row]));
        rsum[m][rg] = 0.f;
      }
    for (int t = 0; t < 8; ++t)
      for (int m = 0; m < 2; ++m)
        for (int rg = 0; rg < 4; ++rg) {
          const float e = __expf((sacc[t][m][rg] - rmax[m][rg]) * 0.125f);
          sacc[t][m][rg] = e;
          rsum[m][rg] += e;
        }
    for (int m = 0; m < 2; ++m)
      for (int rg = 0; rg < 4; ++rg) {
        float v = rsum[m][rg];
        v += __shfl_xor(v, 1);
        v += __shfl_xor(v, 2);
        v += __shfl_xor(v, 4);
        v += __shfl_xor(v, 8);
        rsum[m][rg] = v;
      }
    if (l15 == 0)
      for (int m = 0; m < 2; ++m)
        for (int rg = 0; rg < 4; ++rg)
          ssum[wid][m * 16 + g * 4 + rg] = rsum[m][rg];
    __syncthreads();
    for (int m = 0; m < 2; ++m)
      for (int rg = 0; rg < 4; ++rg) {
        const int row = m * 16 + g * 4 + rg;
        const float inv =
            1.f / (ssum[0][row] + ssum[1][row] + ssum[2][row] + ssum[3][row]);
        for (int t = 0; t < 8; ++t)
          P[row][wid * 128 + t * 16 + l15] = (bf16)(sacc[t][m][rg] * inv);
      }
    // PV: O_w += P[:, wave keys] @ V[wave keys, :]
    const bf16* vbase = vT + (size_t)(b * 16 + h) * 64 * 2048 + j * 512;
    for (int kk = 0; kk < 4; ++kk) {
      const int kb = wid * 128 + kk * 32;
      bf16x8 pa[2];
      for (int m = 0; m < 2; ++m)
        pa[m] = *(const bf16x8*)&P[m * 16 + l15][kb + g * 8];
      for (int n = 0; n < 4; ++n) {
        const bf16x8 vf =
            *(const bf16x8*)(vbase + (size_t)(n * 16 + l15) * 2048 + kb + g * 8);
        for (int m = 0; m < 2; ++m) Oacc[m][n] = MFMA16(pa[m], vf, Oacc[m][n]);
      }
    }
  }

  __syncthreads();  // all waves done with P before aliasing it
  float* Ored = (float*)&P[0][0];  // [4][32][64] fp32 = 32KB
  for (int m = 0; m < 2; ++m)
    for (int n = 0; n < 4; ++n)
      for (int rg = 0; rg < 4; ++rg) {
        const int row = m * 16 + g * 4 + rg, col = n * 16 + l15;
        Ored[wid * 2048 + row * 64 + col] = Oacc[m][n][rg];
      }
  __syncthreads();
  for (int q = 0; q < 8; ++q) {
    const int e = tid * 8 + q;
    const float v =
        0.25f * (Ored[e] + Ored[2048 + e] + Ored[4096 + e] + Ored[6144 + e]);
    ctx[(size_t)(rowbase + (e >> 6)) * 1024 + h * 64 + (e & 63)] = (bf16)v;
  }
}

// ---------------- launch ----------------

extern "C" void kernel_launch(void* const* d_in, const int* in_sizes, int n_in,
                              void* d_out, int out_size, void* d_ws,
                              size_t ws_size, hipStream_t stream) {
  const float* x = (const float*)d_in[0];
  const float* w_qkv = (const float*)d_in[1];
  const float* b_qkv = (const float*)d_in[2];
  const float* w_proj = (const float*)d_in[3];
  const float* b_proj = (const float*)d_in[4];
  float* out = (float*)d_out;

  char* ws = (char*)d_ws;
  bf16* xb     = (bf16*)(ws);                    // 8 MB  [4096,1024]
  bf16* wqkvT  = (bf16*)(ws + (8u << 20));       // 6 MB  [3072,1024]
  bf16* wprojT = (bf16*)(ws + (14u << 20));      // 2 MB  [1024,1024]
  bf16* qkv    = (bf16*)(ws + (16u << 20));      // 24 MB [4096,3072]
  bf16* vT     = (bf16*)(ws + (40u << 20));      // 8 MB  [B,NH,64,2048]
  bf16* ctx    = (bf16*)(ws + (48u << 20));      // 8 MB  [4096,1024]

  hipLaunchKernelGGL(f32_to_bf16_kernel, dim3(4096), dim3(256), 0, stream, x,
                     xb, 4096 * 1024);
  hipLaunchKernelGGL(transpose_to_bf16, dim3(96, 32), dim3(32, 8), 0, stream,
                     w_qkv, wqkvT, 1024, 3072);
  hipLaunchKernelGGL(transpose_to_bf16, dim3(32, 32), dim3(32, 8), 0, stream,
                     w_proj, wprojT, 1024, 1024);
  hipLaunchKernelGGL((gemm_bt<0>), dim3(24, 32), dim3(256), 0, stream, xb,
                     wqkvT, b_qkv, (void*)qkv, vT, 4096, 3072, 1024);
  hipLaunchKernelGGL(attn_kernel, dim3(64, 16, 2), dim3(256), 0, stream, qkv,
                     vT, ctx);
  hipLaunchKernelGGL((gemm_bt<1>), dim3(8, 32), dim3(256), 0, stream, ctx,
                     wprojT, b_proj, (void*)out, (bf16*)nullptr, 4096, 1024,
                     1024);
}

// Round 2
// 213.089 us; speedup vs baseline: 1.1650x; 1.1650x over previous
//
#include <hip/hip_runtime.h>
#include <hip/hip_bf16.h>
#include <stdint.h>

typedef __bf16 bf16;
typedef __bf16 bf16x8 __attribute__((ext_vector_type(8)));
typedef __bf16 bf16x4 __attribute__((ext_vector_type(4)));
typedef float f32x4 __attribute__((ext_vector_type(4)));

#define MFMA16(a, b, c) __builtin_amdgcn_mfma_f32_16x16x32_bf16(a, b, c, 0, 0, 0)

__device__ __forceinline__ void gload_lds16(const void* g, void* l) {
  __builtin_amdgcn_global_load_lds(
      (const __attribute__((address_space(1))) void*)g,
      (__attribute__((address_space(3))) void*)l, 16, 0, 0);
}

// ---------------- prep kernels ----------------

__global__ void f32_to_bf16_kernel(const float* __restrict__ in,
                                   bf16* __restrict__ out, int n) {
  int i = (blockIdx.x * blockDim.x + threadIdx.x) * 4;
  if (i >= n) return;
  const float4 v = *(const float4*)(in + i);
  bf16x4 o = {(bf16)v.x, (bf16)v.y, (bf16)v.z, (bf16)v.w};
  *(bf16x4*)(out + i) = o;
}

// in: fp32 [R][C]  ->  out: bf16 [C][R]
__global__ void transpose_to_bf16(const float* __restrict__ in,
                                  bf16* __restrict__ out, int R, int C) {
  __shared__ float t[32][33];
  const int tx = threadIdx.x, ty = threadIdx.y;
  const int c0 = blockIdx.x * 32, r0 = blockIdx.y * 32;
  for (int i = 0; i < 32; i += 8)
    t[ty + i][tx] = in[(size_t)(r0 + ty + i) * C + c0 + tx];
  __syncthreads();
  for (int i = 0; i < 32; i += 8)
    out[(size_t)(c0 + ty + i) * R + r0 + tx] = (bf16)t[tx][ty + i];
}

// ---------------- GEMM: C[M,N] = A[M,K] * Bt[N,K]^T + bias ----------------
// EPI=0: scatter epilogue -> qp [b,h,s,64], kp [b,h,s,64], vT [b,h,d,s]
// EPI=1: fp32 out (proj)

template <int EPI>
__global__ __launch_bounds__(256, 2) void gemm_bt(
    const bf16* __restrict__ A, const bf16* __restrict__ Bt,
    const float* __restrict__ bias, void* __restrict__ Cout,
    bf16* __restrict__ qp, bf16* __restrict__ kp, bf16* __restrict__ vT,
    int M, int N, int K, int nxb) {
  __shared__ bf16 lA[128 * 64];
  __shared__ bf16 lB[128 * 64];
  const int tid = threadIdx.x;
  const int wid = tid >> 6, lane = tid & 63;
  const int l15 = lane & 15, g = lane >> 4;
  // XCD-chunked swizzle (gridDim.x % 8 == 0)
  const int cpx = gridDim.x >> 3;
  const int wg = (blockIdx.x & 7) * cpx + (blockIdx.x >> 3);
  const int m0 = (wg / nxb) * 128, n0 = (wg % nxb) * 128;
  const int wr = wid >> 1, wc = wid & 1;

  f32x4 acc[4][4] = {};

  const int soff = wid * 4096 + lane * 16;  // byte offset in tile per lane
  for (int kt = 0; kt < K; kt += 64) {
    for (int c = 0; c < 4; ++c) {
      const int off = soff + c * 1024;
      const int e = off >> 1;
      const int r = e >> 6, col = e & 63;
      gload_lds16(A + (size_t)(m0 + r) * K + kt + col, (char*)lA + off);
      gload_lds16(Bt + (size_t)(n0 + r) * K + kt + col, (char*)lB + off);
    }
    asm volatile("s_waitcnt vmcnt(0)" ::: "memory");
    __syncthreads();
    for (int kk = 0; kk < 2; ++kk) {
      const int ko = kk * 32 + g * 8;
      bf16x8 af[4], bfr[4];
      for (int mi = 0; mi < 4; ++mi)
        af[mi] = *(const bf16x8*)(lA + (wr * 64 + mi * 16 + l15) * 64 + ko);
      for (int ni = 0; ni < 4; ++ni)
        bfr[ni] = *(const bf16x8*)(lB + (wc * 64 + ni * 16 + l15) * 64 + ko);
      for (int mi = 0; mi < 4; ++mi)
        for (int ni = 0; ni < 4; ++ni)
          acc[mi][ni] = MFMA16(af[mi], bfr[ni], acc[mi][ni]);
    }
    __syncthreads();
  }

  for (int mi = 0; mi < 4; ++mi) {
    const int rbase = m0 + wr * 64 + mi * 16 + g * 4;
    for (int ni = 0; ni < 4; ++ni) {
      const int cc = n0 + wc * 64 + ni * 16 + l15;
      const float bv = bias[cc];
      const int sec = cc >> 10, hh = (cc >> 6) & 15, d = cc & 63;
      for (int rg = 0; rg < 4; ++rg) {
        const int r = rbase + rg;
        const float v = acc[mi][ni][rg] + bv;
        if (EPI == 0) {
          const bf16 bb = (bf16)v;
          const int b = r >> 11, s = r & 2047;
          const size_t bh = (size_t)(b * 16 + hh);
          if (sec == 0)
            qp[(bh * 2048 + s) * 64 + d] = bb;
          else if (sec == 1)
            kp[(bh * 2048 + s) * 64 + d] = bb;
          else
            vT[(bh * 64 + d) * 2048 + s] = bb;
        } else {
          ((float*)Cout)[(size_t)r * N + cc] = v;
        }
      }
    }
  }
}

// ---------------- attention ----------------
// 1D grid of 2048 blocks (XCD-chunk swizzled), block 256 (4 waves).
// Block: 32 q-rows of one (b,h). Each wave owns a 128-key slice of every
// 512-key chunk. Per chunk: S=QK^T in regs (packed K, coalesced, prefetch) ->
// exact per-chunk softmax -> P to LDS (layout transpose) -> O_w += P @ V.
// Final: cross-wave reduce, *0.25, ctx bf16.

__global__ __launch_bounds__(256, 2) void attn_kernel(
    const bf16* __restrict__ qp, const bf16* __restrict__ kp,
    const bf16* __restrict__ vT, bf16* __restrict__ ctx) {
  __shared__ __align__(16) bf16 P[32][520];
  __shared__ float smax[4][32];
  __shared__ float ssum[4][32];

  const int tid = threadIdx.x;
  const int wid = tid >> 6, lane = tid & 63;
  const int l15 = lane & 15, g = lane >> 4;
  // XCD-chunked swizzle: each XCD gets 4 consecutive (b,h) pairs
  const int wg = (blockIdx.x & 7) * 256 + (blockIdx.x >> 3);
  const int qt = wg & 63, h = (wg >> 6) & 15, b = wg >> 10;
  const size_t bh = (size_t)(b * 16 + h);
  const int rowbase = b * 2048 + qt * 32;

  const bf16* qptr = qp + (bh * 2048 + (size_t)qt * 32) * 64;
  bf16x8 Qf[2][2];
  for (int m = 0; m < 2; ++m)
    for (int kk = 0; kk < 2; ++kk)
      Qf[m][kk] = *(const bf16x8*)(qptr + (m * 16 + l15) * 64 + kk * 32 + g * 8);

  f32x4 Oacc[2][4] = {};

  for (int j = 0; j < 4; ++j) {
    // per-wave K pointer: this wave's 128 keys of chunk j, packed layout
    const bf16* kw =
        kp + (bh * 2048 + (size_t)j * 512 + wid * 128 + l15) * 64 + g * 8;
    f32x4 sacc[8][2] = {};
    bf16x8 kc0 = *(const bf16x8*)(kw);
    bf16x8 kc1 = *(const bf16x8*)(kw + 32);
    for (int t = 0; t < 8; ++t) {
      bf16x8 kn0, kn1;
      if (t < 7) {
        kn0 = *(const bf16x8*)(kw + (size_t)(t + 1) * 16 * 64);
        kn1 = *(const bf16x8*)(kw + (size_t)(t + 1) * 16 * 64 + 32);
      }
      sacc[t][0] = MFMA16(Qf[0][0], kc0, sacc[t][0]);
      sacc[t][1] = MFMA16(Qf[1][0], kc0, sacc[t][1]);
      sacc[t][0] = MFMA16(Qf[0][1], kc1, sacc[t][0]);
      sacc[t][1] = MFMA16(Qf[1][1], kc1, sacc[t][1]);
      kc0 = kn0;
      kc1 = kn1;
    }
    float rmax[2][4], rsum[2][4];
    for (int m = 0; m < 2; ++m)
      for (int rg = 0; rg < 4; ++rg) {
        float v = sacc[0][m][rg];
        for (int t = 1; t < 8; ++t) v = fmaxf(v, sacc[t][m][rg]);
        v = fmaxf(v, __shfl_xor(v, 1));
        v = fmaxf(v, __shfl_xor(v, 2));
        v = fmaxf(v, __shfl_xor(v, 4));
        v = fmaxf(v, __shfl_xor(v, 8));
        rmax[m][rg] = v;
      }
    if (l15 == 0)
      for (int m = 0; m < 2; ++m)
        for (int rg = 0; rg < 4; ++rg)
          smax[wid][m * 16 + g * 4 + rg] = rmax[m][rg];
    __syncthreads();
    for (int m = 0; m < 2; ++m)
      for (int rg = 0; rg < 4; ++rg) {
        const int row = m * 16 + g * 4 + rg;
        rmax[m][rg] = fmaxf(fmaxf(smax[0][row], smax[1][row]),
                            fmaxf(smax[2][row], smax[3][row]));
        rsum[m][rg] = 0.f;
      }
    for (int t = 0; t < 8; ++t)
      for (int m = 0; m < 2; ++m)
        for (int rg = 0; rg < 4; ++rg) {
          const float e = __expf((sacc[t][m][rg] - rmax[m][rg]) * 0.125f);
          sacc[t][m][rg] = e;
          rsum[m][rg] += e;
        }
    for (int m = 0; m < 2; ++m)
      for (int rg = 0; rg < 4; ++rg) {
        float v = rsum[m][rg];
        v += __shfl_xor(v, 1);
        v += __shfl_xor(v, 2);
        v += __shfl_xor(v, 4);
        v += __shfl_xor(v, 8);
        rsum[m][rg] = v;
      }
    if (l15 == 0)
      for (int m = 0; m < 2; ++m)
        for (int rg = 0; rg < 4; ++rg)
          ssum[wid][m * 16 + g * 4 + rg] = rsum[m][rg];
    __syncthreads();
    for (int m = 0; m < 2; ++m)
      for (int rg = 0; rg < 4; ++rg) {
        const int row = m * 16 + g * 4 + rg;
        const float inv =
            1.f / (ssum[0][row] + ssum[1][row] + ssum[2][row] + ssum[3][row]);
        for (int t = 0; t < 8; ++t)
          P[row][wid * 128 + t * 16 + l15] = (bf16)(sacc[t][m][rg] * inv);
      }
    // PV: O_w += P[:, wave keys] @ V[wave keys, :]
    const bf16* vbase = vT + bh * 64 * 2048 + (size_t)j * 512;
    for (int kk = 0; kk < 4; ++kk) {
      const int kb = wid * 128 + kk * 32;
      bf16x8 pa[2];
      for (int m = 0; m < 2; ++m)
        pa[m] = *(const bf16x8*)&P[m * 16 + l15][kb + g * 8];
      for (int n = 0; n < 4; ++n) {
        const bf16x8 vf =
            *(const bf16x8*)(vbase + (size_t)(n * 16 + l15) * 2048 + kb + g * 8);
        for (int m = 0; m < 2; ++m) Oacc[m][n] = MFMA16(pa[m], vf, Oacc[m][n]);
      }
    }
  }

  __syncthreads();  // all waves done with P before aliasing it
  float* Ored = (float*)&P[0][0];  // [4][32][64] fp32 = 32KB
  for (int m = 0; m < 2; ++m)
    for (int n = 0; n < 4; ++n)
      for (int rg = 0; rg < 4; ++rg) {
        const int row = m * 16 + g * 4 + rg, col = n * 16 + l15;
        Ored[wid * 2048 + row * 64 + col] = Oacc[m][n][rg];
      }
  __syncthreads();
  for (int q = 0; q < 8; ++q) {
    const int e = tid * 8 + q;
    const float v =
        0.25f * (Ored[e] + Ored[2048 + e] + Ored[4096 + e] + Ored[6144 + e]);
    ctx[(size_t)(rowbase + (e >> 6)) * 1024 + h * 64 + (e & 63)] = (bf16)v;
  }
}

// ---------------- launch ----------------

extern "C" void kernel_launch(void* const* d_in, const int* in_sizes, int n_in,
                              void* d_out, int out_size, void* d_ws,
                              size_t ws_size, hipStream_t stream) {
  const float* x = (const float*)d_in[0];
  const float* w_qkv = (const float*)d_in[1];
  const float* b_qkv = (const float*)d_in[2];
  const float* w_proj = (const float*)d_in[3];
  const float* b_proj = (const float*)d_in[4];
  float* out = (float*)d_out;

  char* ws = (char*)d_ws;
  bf16* xb     = (bf16*)(ws);                 // 8 MB  [4096,1024]
  bf16* wqkvT  = (bf16*)(ws + (8u << 20));    // 6 MB  [3072,1024]
  bf16* wprojT = (bf16*)(ws + (14u << 20));   // 2 MB  [1024,1024]
  bf16* qp     = (bf16*)(ws + (16u << 20));   // 8 MB  [B,NH,S,64]
  bf16* kp     = (bf16*)(ws + (24u << 20));   // 8 MB  [B,NH,S,64]
  bf16* vT     = (bf16*)(ws + (32u << 20));   // 8 MB  [B,NH,64,S]
  bf16* ctx    = (bf16*)(ws + (40u << 20));   // 8 MB  [4096,1024]

  hipLaunchKernelGGL(f32_to_bf16_kernel, dim3(4096), dim3(256), 0, stream, x,
                     xb, 4096 * 1024);
  hipLaunchKernelGGL(transpose_to_bf16, dim3(96, 32), dim3(32, 8), 0, stream,
                     w_qkv, wqkvT, 1024, 3072);
  hipLaunchKernelGGL(transpose_to_bf16, dim3(32, 32), dim3(32, 8), 0, stream,
                     w_proj, wprojT, 1024, 1024);
  hipLaunchKernelGGL((gemm_bt<0>), dim3(24 * 32), dim3(256), 0, stream, xb,
                     wqkvT, b_qkv, (void*)nullptr, qp, kp, vT, 4096, 3072,
                     1024, 24);
  hipLaunchKernelGGL(attn_kernel, dim3(2048), dim3(256), 0, stream, qp, kp, vT,
                     ctx);
  hipLaunchKernelGGL((gemm_bt<1>), dim3(8 * 32), dim3(256), 0, stream, ctx,
                     wprojT, b_proj, (void*)out, (bf16*)nullptr, (bf16*)nullptr,
                     (bf16*)nullptr, 4096, 1024, 1024, 8);
}